// Round 6
// baseline (110.234 us; speedup 1.0000x reference)
//
#include <hip/hip_runtime.h>
#include <stdint.h>

typedef float  float4v  __attribute__((ext_vector_type(4)));
typedef long long llong2v __attribute__((ext_vector_type(2)));
typedef unsigned int uint4v __attribute__((ext_vector_type(4)));

// Problem constants (N=8192, n_in=256, m=256, k=8)
// GEMM: [8192 x 512] x [512 x 8192] in fp8 e4m3 with fused LSTM epilogue.
// W pre-scaled by 16 (e4m3 normal range); acc scaled by 1/16 in epilogue.
// Identical K-permutation on A and B => correct for any HW k-mapping.

__device__ __forceinline__ unsigned int pk4fp8(float a, float b, float c, float d) {
  unsigned int p = (unsigned int)__builtin_amdgcn_cvt_pk_fp8_f32(a, b, 0, false);
  p = (unsigned int)__builtin_amdgcn_cvt_pk_fp8_f32(c, d, (int)p, true);
  return p;
}

__device__ __forceinline__ float sigm(float x) {
  return __builtin_amdgcn_rcpf(1.0f + __expf(-x));
}
__device__ __forceinline__ float tanh_(float x) {
  return fmaf(2.0f, __builtin_amdgcn_rcpf(1.0f + __expf(-2.0f * x)), -1.0f);
}

__device__ __forceinline__ void gll16(const void* g, void* l) {
  __builtin_amdgcn_global_load_lds((const __attribute__((address_space(1))) void*)g,
                                   (__attribute__((address_space(3))) void*)l, 16, 0, 0);
}

#define BARRIER   asm volatile("s_barrier" ::: "memory")
#define WAITLGKM  asm volatile("s_waitcnt lgkmcnt(0)" ::: "memory")
#define WAITVM4   asm volatile("s_waitcnt vmcnt(4)" ::: "memory")
#define WAITVM0   asm volatile("s_waitcnt vmcnt(0)" ::: "memory")
#define PRIO1     __builtin_amdgcn_s_setprio(1)
#define PRIO0     __builtin_amdgcn_s_setprio(0)

// ------------- P1+L fused: A = [x|h] fp8 K-granule-permuted + logits --------------
__global__ void prep_logits(const float* __restrict__ x, const float* __restrict__ h,
                            const float* __restrict__ u, const float* __restrict__ Wxz,
                            const float* __restrict__ Whz, const float* __restrict__ bxz,
                            const void* __restrict__ taup,
                            uint8_t* __restrict__ A,
                            float* __restrict__ z_out, float* __restrict__ qz_out) {
  int lane = threadIdx.x & 63;
  int n = blockIdx.x * 4 + (threadIdx.x >> 6);
  float4v xv = *(const float4v*)(x + (size_t)n * 256 + lane * 4);
  float4v hv = *(const float4v*)(h + (size_t)n * 256 + lane * 4);

  // fp8 A write: lane i covers orig k = 4i..4i+3 (x) and 256+4i.. (h)
  {
    unsigned int px = pk4fp8(xv[0], xv[1], xv[2], xv[3]);
    unsigned int ph = pk4fp8(hv[0], hv[1], hv[2], hv[3]);
    int koff = ((lane >> 4) << 6) + (((lane >> 1) & 3) << 4)
             + (((lane >> 3) & 1) << 3) + ((lane & 1) << 2);
    uint8_t* dst = A + (size_t)n * 512 + koff;
    *(unsigned int*)dst = px;
    *(unsigned int*)(dst + 256) = ph;
  }

  // ---- logits
  float p[8];
#pragma unroll
  for (int j = 0; j < 8; ++j) p[j] = 0.0f;
#pragma unroll
  for (int ii = 0; ii < 4; ++ii) {
    int i = lane * 4 + ii;
    float xs = xv[ii], hs = hv[ii];
#pragma unroll
    for (int j = 0; j < 8; ++j)
      p[j] += xs * Wxz[i * 8 + j] + hs * Whz[i * 8 + j];
  }
#pragma unroll
  for (int j = 0; j < 8; ++j)
    for (int off = 32; off > 0; off >>= 1) p[j] += __shfl_down(p[j], off, 64);

  if (lane == 0) {
    int   iv = ((const int*)taup)[0];
    float fv = ((const float*)taup)[0];
    float tau = (iv >= 1 && iv < 100000) ? (float)iv : fv;
    float tinv = 1.0f / tau;

    float logit[8], e[8];
    float mx = -1e30f;
#pragma unroll
    for (int j = 0; j < 8; ++j) { logit[j] = p[j] + bxz[j]; mx = fmaxf(mx, logit[j]); }
    float s = 0.0f;
#pragma unroll
    for (int j = 0; j < 8; ++j) { e[j] = __expf(logit[j] - mx); s += e[j]; }
    float inv = 1.0f / s;
#pragma unroll
    for (int j = 0; j < 8; ++j) qz_out[(size_t)n * 8 + j] = e[j] * inv;

    float t[8];
    float mt = -1e30f;
#pragma unroll
    for (int j = 0; j < 8; ++j) {
      float uu = u[(size_t)n * 8 + j];
      float g = -__logf(-__logf(uu + 1e-10f) + 1e-10f);
      t[j] = (logit[j] + g) * tinv;
      mt = fmaxf(mt, t[j]);
    }
    float s2 = 0.0f;
#pragma unroll
    for (int j = 0; j < 8; ++j) { e[j] = __expf(t[j] - mt); s2 += e[j]; }
    float inv2 = 1.0f / s2;
#pragma unroll
    for (int j = 0; j < 8; ++j) z_out[(size_t)n * 8 + j] = e[j] * inv2;
  }
}

// ---------------- P2: Bt[p][512B] fp8, col-permuted + K-granule-permuted ----------
// p(C) = (mm>>3)*256 + (g>>1)*128 + (g&1)*64 + (kk>>1)*16 + (kk&1)*8 + (mm&7)
__global__ void prep_Bt(const float* __restrict__ Wx, const float* __restrict__ Wh,
                        uint8_t* __restrict__ Bt) {
  __shared__ float tile[64][64];
  int tid = threadIdx.x;
  int wi = blockIdx.x & 7;            // 64-k window
  int C0 = (blockIdx.x >> 3) << 6;    // 64-col group
#pragma unroll
  for (int qq = 0; qq < 16; ++qq) {
    int flat = qq * 256 + tid;
    int r = flat >> 6, c = flat & 63;
    int ig = wi * 64 + r;
    float v = (ig < 256) ? Wx[(size_t)ig * 8192 + C0 + c]
                         : Wh[(size_t)(ig - 256) * 8192 + C0 + c];
    tile[r][c] = v * 16.0f;
  }
  __syncthreads();
  int c = tid & 63, q = tid >> 6;
  int C = C0 + c;
  int g = C >> 11, kk = (C >> 8) & 7, mm = C & 255;
  int p = ((mm >> 3) << 8) | ((g >> 1) << 7) | ((g & 1) << 6)
        | ((kk >> 1) << 4) | ((kk & 1) << 3) | (mm & 7);
  uint4v o;
  o[0] = pk4fp8(tile[q * 8 + 0][c], tile[q * 8 + 1][c], tile[q * 8 + 2][c], tile[q * 8 + 3][c]);
  o[1] = pk4fp8(tile[q * 8 + 4][c], tile[q * 8 + 5][c], tile[q * 8 + 6][c], tile[q * 8 + 7][c]);
  o[2] = pk4fp8(tile[32 + q * 8 + 0][c], tile[32 + q * 8 + 1][c], tile[32 + q * 8 + 2][c], tile[32 + q * 8 + 3][c]);
  o[3] = pk4fp8(tile[32 + q * 8 + 4][c], tile[32 + q * 8 + 5][c], tile[32 + q * 8 + 6][c], tile[32 + q * 8 + 7][c]);
  *(uint4v*)(Bt + (size_t)p * 512 + wi * 64 + q * 16) = o;
}

// ---------------- G: fp8 256x256-tile single-phase-per-kt GEMM + epilogue ---------
// 8 waves = 2M x 4N. Rows: ha*128 + j*32 + wm*16 + gl*4 + r ; cols: hb*128 + n2*64 + wn*16 + ml
// gate g = hb*2+n2 ; kk = wn*2+(ml>>3) ; mml = ml&7
__global__ __launch_bounds__(512, 2) void gates_kernel(
    const uint8_t* __restrict__ A,    // [8192][512B] fp8, K-granule layout
    const uint8_t* __restrict__ Bt,   // [8192][512B] fp8, col+K-granule layout
    const float* __restrict__ c0g,    // [8192][256]
    const float* __restrict__ bias,   // [8192]
    const float* __restrict__ zg,     // [8192][8]
    float* __restrict__ h_out, float* __restrict__ c_out) {
  __shared__ char smem[65536];  // A: 2 x 16KB @0 ; B: 2 x 16KB @32768

  const int tid = threadIdx.x;
  const int lane = tid & 63, ml = lane & 15, gl = lane >> 4;
  const int wid = tid >> 6, wm = wid >> 2, wn = wid & 3;

  // XCD-stripe grid mapping (verified R3): xcd owns rb {4x..4x+3}, cb outer
  const int xcd = blockIdx.x & 7;
  const int j_  = blockIdx.x >> 3;
  const int cb  = j_ >> 2;
  const int rb  = (xcd << 2) | (j_ & 3);
  const int row0 = rb << 8;

  const uint8_t* Abp = A + (size_t)rb * 131072;   // 256 rows x 512B
  const uint8_t* Bbp = Bt + (size_t)cb * 131072;

  // staging: full tile (A 16KB + B 16KB) per kt; thread covers granules tid, tid+512
  const int ssrc = (tid >> 2) * 512 + (tid & 3) * 16;

  // fragment LDS bases (contiguous 1KB per 16-row group: conflict-free)
  const char* pa = smem + ((wm << 4) + ml) * 64 + (gl << 4);
  const char* pb = smem + 32768 + ((wn << 4) + ml) * 64 + (gl << 4);

#define STGF(KTS) do { \
    const int kb_ = (KTS) & 1; \
    const uint8_t* sa_ = Abp + ssrc + ((KTS) & 7) * 64; \
    const uint8_t* sb_ = Bbp + ssrc + ((KTS) & 7) * 64; \
    char* da_ = smem + kb_ * 16384 + (tid << 4); \
    char* db_ = smem + 32768 + kb_ * 16384 + (tid << 4); \
    gll16(sa_, da_); gll16(sa_ + 65536, da_ + 8192); \
    gll16(sb_, db_); gll16(sb_ + 65536, db_ + 8192); \
  } while (0)

#define RDA(KB, HF) { _Pragma("unroll") for (int j = 0; j < 4; ++j) \
    af[j] = *(const llong2v*)(pa + (KB) * 16384 + (HF) * 8192 + j * 2048); }
#define RDB(KB, HF, BF) { _Pragma("unroll") for (int n2 = 0; n2 < 2; ++n2) \
    BF[n2] = *(const llong2v*)(pb + (KB) * 16384 + (HF) * 8192 + n2 * 4096); }
#define MM16(AH, BH, BF) { _Pragma("unroll") for (int j = 0; j < 4; ++j) \
    _Pragma("unroll") for (int n2 = 0; n2 < 2; ++n2) { \
      acc[AH][BH][j][n2] = __builtin_amdgcn_mfma_f32_16x16x32_fp8_fp8(af[j][0], BF[n2][0], acc[AH][BH][j][n2], 0, 0, 0); \
      acc[AH][BH][j][n2] = __builtin_amdgcn_mfma_f32_16x16x32_fp8_fp8(af[j][1], BF[n2][1], acc[AH][BH][j][n2], 0, 0, 0); } }

  float4v acc[2][2][4][2];   // [ha][hb][j][n2]
#pragma unroll
  for (int a = 0; a < 2; ++a)
#pragma unroll
    for (int b = 0; b < 2; ++b)
#pragma unroll
      for (int j = 0; j < 4; ++j)
#pragma unroll
        for (int c = 0; c < 2; ++c)
#pragma unroll
          for (int r = 0; r < 4; ++r) acc[a][b][j][c][r] = 0.0f;

  llong2v af[4];
  llong2v bf0[2], bf1[2];

  // prologue: stage kt0 + kt1 (8 loads); own kt0 done at vmcnt(4); barrier = all
  STGF(0); STGF(1);
  WAITVM4;
  BARRIER;

#pragma unroll
  for (int kt = 0; kt < 8; ++kt) {
    const int kb = kt & 1;

    RDA(kb, 0); RDB(kb, 0, bf0); RDB(kb, 1, bf1);   // 8 reads
    WAITLGKM;
    PRIO1; MM16(0, 0, bf0); MM16(0, 1, bf1); PRIO0;
    RDA(kb, 1);                                      // 4 reads
    WAITLGKM;
    PRIO1; MM16(1, 1, bf1); MM16(1, 0, bf0); PRIO0;

    BARRIER;                       // all waves' reads of slot kb complete
    if (kt <= 5) {
      STGF(kt + 2);                // overwrite slot kb with kt+2
      WAITVM4;                     // own kt+1 loads landed (kt+2's 4 remain)
      BARRIER;                     // all waves' kt+1 loads landed
    } else if (kt == 6) {
      WAITVM0;                     // drain kt7
      BARRIER;
    }
  }
#undef STGF
#undef RDA
#undef RDB
#undef MM16

  // ---------------- fused LSTM epilogue (LDS reused; pbuf stride 9 pads banks) ----
  const int kkl = (wn << 1) | (ml >> 3);
  const int mml = ml & 7;
  {
    const int mmg = (cb << 3) + mml;
    const float bI = bias[0 * 2048 + kkl * 256 + mmg];
    const float bG = bias[1 * 2048 + kkl * 256 + mmg];
    const float bF = bias[2 * 2048 + kkl * 256 + mmg];
    const float bO = bias[3 * 2048 + kkl * 256 + mmg];
    const float s16 = 0.0625f;   // undo W*16 pre-scale

    float hpart[2][4][4], cpart[2][4][4];
#pragma unroll
    for (int ha = 0; ha < 2; ++ha) {
#pragma unroll
      for (int j = 0; j < 4; ++j) {
        const int nb = row0 + ha * 128 + j * 32 + wm * 16 + gl * 4;
        // gates in-register: I=acc[ha][0][j][0], G=[0][1], F=[1][0], O=[1][1]
#pragma unroll
        for (int r = 0; r < 4; ++r) {
          const int nrow = nb + r;
          float I = fmaf(acc[ha][0][j][0][r], s16, bI);
          float G = fmaf(acc[ha][0][j][1][r], s16, bG);
          float F = fmaf(acc[ha][1][j][0][r], s16, bF);
          float O = fmaf(acc[ha][1][j][1][r], s16, bO);
          float c0v = c0g[(size_t)nrow * 256 + mmg];
          float ct = fmaf(sigm(F), c0v, sigm(I) * tanh_(G));
          float ht = sigm(O) * tanh_(ct);
          float zv = zg[(size_t)nrow * 8 + kkl];
          float h1 = zv * ht, c1 = zv * ct;
          h1 += __shfl_xor(h1, 8, 64);    // combine the wave's 2 kk
          c1 += __shfl_xor(c1, 8, 64);
          hpart[ha][j][r] = h1;
          cpart[ha][j][r] = c1;
        }
      }
    }

    float* pbuf = (float*)smem;   // [wn][256][9] floats = 36KB
    const bool wr = ((ml & 8) == 0);
    // ---- pass 1: h
    if (wr) {
#pragma unroll
      for (int ha = 0; ha < 2; ++ha)
#pragma unroll
        for (int j = 0; j < 4; ++j)
#pragma unroll
          for (int r = 0; r < 4; ++r) {
            int rloc = ha * 128 + j * 32 + wm * 16 + gl * 4 + r;
            pbuf[wn * 2304 + rloc * 9 + mml] = hpart[ha][j][r];
          }
    }
    WAITLGKM; BARRIER;
#pragma unroll
    for (int i = 0; i < 4; ++i) {
      int idx = (i << 9) + tid;
      int rloc = idx >> 3, mm2 = idx & 7;
      float v = pbuf[rloc * 9 + mm2] + pbuf[2304 + rloc * 9 + mm2]
              + pbuf[4608 + rloc * 9 + mm2] + pbuf[6912 + rloc * 9 + mm2];
      h_out[(size_t)(row0 + rloc) * 256 + (cb << 3) + mm2] = v;
    }
    WAITLGKM; BARRIER;
    // ---- pass 2: c
    if (wr) {
#pragma unroll
      for (int ha = 0; ha < 2; ++ha)
#pragma unroll
        for (int j = 0; j < 4; ++j)
#pragma unroll
          for (int r = 0; r < 4; ++r) {
            int rloc = ha * 128 + j * 32 + wm * 16 + gl * 4 + r;
            pbuf[wn * 2304 + rloc * 9 + mml] = cpart[ha][j][r];
          }
    }
    WAITLGKM; BARRIER;
#pragma unroll
    for (int i = 0; i < 4; ++i) {
      int idx = (i << 9) + tid;
      int rloc = idx >> 3, mm2 = idx & 7;
      float v = pbuf[rloc * 9 + mm2] + pbuf[2304 + rloc * 9 + mm2]
              + pbuf[4608 + rloc * 9 + mm2] + pbuf[6912 + rloc * 9 + mm2];
      c_out[(size_t)(row0 + rloc) * 256 + (cb << 3) + mm2] = v;
    }
  }
}

extern "C" void kernel_launch(void* const* d_in, const int* in_sizes, int n_in,
                              void* d_out, int out_size, void* d_ws, size_t ws_size,
                              hipStream_t stream) {
  const float* x   = (const float*)d_in[0];
  const float* h0  = (const float*)d_in[1];
  const float* c0  = (const float*)d_in[2];
  const float* u   = (const float*)d_in[3];
  const float* Wxz = (const float*)d_in[4];
  const float* Whz = (const float*)d_in[5];
  const float* Wx4 = (const float*)d_in[6];
  const float* Wh4 = (const float*)d_in[7];
  const float* bxz = (const float*)d_in[8];
  const float* b4  = (const float*)d_in[9];
  const void*  tau = d_in[10];

  float* out    = (float*)d_out;
  float* z_out  = out;                       // [8192][8]
  float* qz_out = out + 65536;               // [8192][8]
  float* h_out  = out + 131072;              // [8192][256]
  float* c_out  = out + 131072 + 2097152;    // [8192][256]

  uint8_t* A  = (uint8_t*)d_ws;              // 4MB fp8
  uint8_t* Bt = A + 4194304;                 // 4MB fp8

  prep_logits<<<2048, 256, 0, stream>>>(x, h0, u, Wxz, Whz, bxz, tau, A, z_out, qz_out);
  prep_Bt<<<1024, 256, 0, stream>>>(Wx4, Wh4, Bt);
  gates_kernel<<<1024, 512, 0, stream>>>(A, Bt, c0, b4, z_out, h_out, c_out);
}